// Round 14
// baseline (296.203 us; speedup 1.0000x reference)
//
#include <hip/hip_runtime.h>
#include <cstdint>

#define NH 8
#define HD 96
#define CDIM 768
#define BQ 2
#define T0 8
#define H0 56
#define W0 56
#define L0 (T0*H0*W0)     // 25088
#define HP_Q 28
#define WP_Q 28
#define LQ (T0*HP_Q*WP_Q) // 6272
#define HP_K 7
#define WP_K 7
#define LK (T0*HP_K*WP_K) // 392
#define LKP 416           // kv padded to multiple of 32
#define SCALE 0.10206207261596577f
#define NYC 20
#define MKV 6400          // 2*8*400 gathered kv rows (50 x 128)
#define NBQ 2352          // Q-gemm blocks: 392 bm x 6 bn
#define NBKV 600          // KV-gemm blocks: 50 bm x 12 bn

typedef __bf16 bf16;
typedef bf16 bf16x4 __attribute__((ext_vector_type(4)));
typedef bf16 bf16x8 __attribute__((ext_vector_type(8)));
typedef float f32x4 __attribute__((ext_vector_type(4)));
typedef float f4 __attribute__((ext_vector_type(4)));

#define GPTR(x) ((const __attribute__((address_space(1))) void*)(x))
#define LPTR(x) ((__attribute__((address_space(3))) void*)(x))

// fast erf-GELU: A&S 7.1.27 rational erf approx, |err(erf)| <= 5e-4 (<< bf16 rounding)
__device__ __forceinline__ float fast_gelu(float x) {
    float z = __builtin_fabsf(x) * 0.7071067811865476f;
    float p = 1.f + z*(0.278393f + z*(0.230389f + z*(0.000972f + z*0.078108f)));
    p = p * p;
    p = p * p;
    float e = 1.f - __builtin_amdgcn_rcpf(p);   // erf(|x|/sqrt2)
    float erfv = (x < 0.f) ? -e : e;
    return 0.5f * x * (1.f + erfv);
}

// ---------------- fused fp32 -> bf16 conversion (x, qkv_w, proj_w) -----------------
#define NX4 9633792
#define NW4 442368
#define NP4 147456
__global__ void cvt_all(const f4* __restrict__ x, const f4* __restrict__ wq,
                        const f4* __restrict__ wp, bf16x4* __restrict__ xo,
                        bf16x4* __restrict__ wqo, bf16x4* __restrict__ wpo) {
    const long total = (long)NX4 + NW4 + NP4;
    long stride = (long)gridDim.x * blockDim.x;
    for (long i = (long)blockIdx.x * blockDim.x + threadIdx.x; i < total; i += stride) {
        f4 v; bf16x4* o;
        if (i < NX4)            { v = x[i];              o = xo + i; }
        else if (i < NX4 + NW4) { v = wq[i - NX4];       o = wqo + (i - NX4); }
        else                    { v = wp[i - NX4 - NW4]; o = wpo + (i - NX4 - NW4); }
        bf16x4 t;
        t[0] = (bf16)v[0]; t[1] = (bf16)v[1]; t[2] = (bf16)v[2]; t[3] = (bf16)v[3];
        *o = t;
    }
}

// map compact grid index (0..19) -> original spatial coord (y or x)
__device__ __forceinline__ int cmap(int i) {
    return ((i + 1) / 3) * 8 + (i + 1) % 3 - 1;
}

// ======== merged Q + KV 128x128 GEMM, BK=32 dbuf (m97-class occupancy) =============
// blocks [0, NBQ):        Q.  M=50176, N=768 (6 bn), GELU, scatter [16][L0][96]
// blocks [NBQ, NBQ+NBKV): KV. M=6400 gathered rows, N=1536 (12 bn), GELU,
//                             compact store [part][b*8+nh][t*400+rr][96]
// LDS: 2 bufs x (A 8KB + B 8KB) = 32KB; epilogue tls 34.8KB -> 4 blocks/CU.
// Rows are 64B (4 chunks of 8 bf16): source swizzle chunk ^= (row>>1)&3;
// frag read slot = g ^ ((row>>1)&3). Counted vmcnt(4), two-barrier K-loop (24 tiles).
__global__ __launch_bounds__(256) void gemm_qkv(
    const bf16* __restrict__ A, const bf16* __restrict__ Wq,
    const float* __restrict__ bias_q, bf16* __restrict__ OutQ,
    bf16* __restrict__ OutKV)
{
    __shared__ bf16 sh[17408];       // 34816 B; bufs at [0,8192) and [8192,16384)
    const int tid = threadIdx.x;
    const int lane = tid & 63;
    const int w = tid >> 6;
    const int wr = w >> 1, wc = w & 1;
    const int arow = lane & 15;
    const int g = lane >> 4;
    const int K = 768;

    // T1: XCD-chunked bijective swizzle over the merged grid (2952 = 8*369)
    const int nwg = gridDim.x;
    const int q_ = nwg >> 3, r_ = nwg & 7;
    const int xcd = blockIdx.x & 7, off = blockIdx.x >> 3;
    const int swz = (xcd < r_ ? xcd*(q_+1) : r_*(q_+1) + (xcd - r_)*q_) + off;

    const bool isQ = swz < NBQ;
    const int idx = isQ ? swz : swz - NBQ;
    const int NBN = isQ ? 6 : 12;
    const long bm = idx / NBN, bn = idx % NBN;
    const bf16* B = isQ ? Wq : Wq + (size_t)768*768;
    const float* bias = isQ ? bias_q : bias_q + 768;

    f32x4 acc[4][4];
#pragma unroll
    for (int i = 0; i < 4; ++i)
#pragma unroll
        for (int j = 0; j < 4; ++j) acc[i][j] = (f32x4){0.f,0.f,0.f,0.f};

    // staging: round s covers rows s*64 + (tid>>2); chunk slot tid&3 (8 bf16 each)
    const int srow = tid >> 2;                       // 0..63
    const int csa = (tid & 3) ^ ((tid >> 3) & 3);    // source chunk (involution w/ row)
    long aoff2[2];
#pragma unroll
    for (int s = 0; s < 2; ++s) {
        int rA = (int)bm*128 + s*64 + srow;
        if (!isQ) {
            int b = rA / 3200; int r = rA - b*3200;
            int t = r / 400;  int rr = r - t*400;
            int yi = rr / NYC, xi = rr - yi*NYC;
            aoff2[s] = ((long)b*L0 + (t*H0 + cmap(yi))*W0 + cmap(xi)) * (long)K;
        } else {
            aoff2[s] = (long)rA * K;
        }
    }
    const bf16* Bg = B + (bn*128 + srow)*(long)K + csa*8;

    auto stage = [&](int buf, int kt) {
        bf16* ldsA = sh + buf*8192;
        bf16* ldsB = sh + buf*8192 + 4096;
#pragma unroll
        for (int s = 0; s < 2; ++s) {
            __builtin_amdgcn_global_load_lds(GPTR(A + aoff2[s] + kt*32 + csa*8),
                                             LPTR(ldsA + s*2048 + tid*8), 16, 0, 0);
            __builtin_amdgcn_global_load_lds(GPTR(Bg + (long)kt*32 + (long)s*64*K),
                                             LPTR(ldsB + s*2048 + tid*8), 16, 0, 0);
        }
    };
    auto compute = [&](int buf) {
        const bf16* ldsA = sh + buf*8192;
        const bf16* ldsB = sh + buf*8192 + 4096;
        bf16x8 af[4], bfr[4];
#pragma unroll
        for (int i = 0; i < 4; ++i) {
            int R = wr*64 + i*16 + arow;
            af[i] = *(const bf16x8*)&ldsA[R*32 + ((g ^ ((R >> 1) & 3))*8)];
        }
#pragma unroll
        for (int j = 0; j < 4; ++j) {
            int R = wc*64 + j*16 + arow;
            bfr[j] = *(const bf16x8*)&ldsB[R*32 + ((g ^ ((R >> 1) & 3))*8)];
        }
        __builtin_amdgcn_s_setprio(1);
#pragma unroll
        for (int i = 0; i < 4; ++i)
#pragma unroll
            for (int j = 0; j < 4; ++j)
                acc[i][j] = __builtin_amdgcn_mfma_f32_16x16x32_bf16(af[i], bfr[j], acc[i][j], 0, 0, 0);
        __builtin_amdgcn_s_setprio(0);
    };

    const int nkt = K / 32;   // 24
    stage(0, 0);
    for (int kt = 0; kt < nkt; ++kt) {
        if (kt + 1 < nkt) {
            stage((kt + 1) & 1, kt + 1);
            asm volatile("s_waitcnt vmcnt(4)" ::: "memory");   // kt's 4 loads landed
        } else {
            asm volatile("s_waitcnt vmcnt(0)" ::: "memory");
        }
        __builtin_amdgcn_s_barrier();
        __builtin_amdgcn_sched_barrier(0);
        compute(kt & 1);
        __builtin_amdgcn_sched_barrier(0);
        __builtin_amdgcn_s_barrier();
    }

    // ---------------- epilogue: LDS transpose + GELU + coalesced bf16x8 stores ------
    __syncthreads();
    bf16* tls = sh;                        // 128 x 136 bf16 = 34816 B
#pragma unroll
    for (int j = 0; j < 4; ++j) {
        const int colb = (int)bn*128 + wc*64 + j*16;
        const int lcol = wc*64 + j*16 + (lane & 15);
        const float bcol = bias[colb + (lane & 15)];
#pragma unroll
        for (int i = 0; i < 4; ++i) {
            int lrow0 = wr*64 + i*16 + ((lane>>4)<<2);
#pragma unroll
            for (int r = 0; r < 4; ++r)
                tls[(lrow0 + r)*136 + lcol] = (bf16)fast_gelu(acc[i][j][r] + bcol);
        }
    }
    __syncthreads();
#pragma unroll
    for (int it = 0; it < 8; ++it) {
        int idx2 = it*256 + tid;
        int mloc = idx2 >> 4;
        int ck = idx2 & 15;
        bf16x8 v = *(const bf16x8*)&tls[mloc*136 + ck*8];
        int m = (int)bm*128 + mloc;
        int col = (int)bn*128 + ck*8;
        if (isQ) {
            int nh = col / HD;
            int c = col - nh*HD;
            int bflag = m >= L0;              // M = 2*L0
            int l = m - (bflag ? L0 : 0);
            size_t addr = ((size_t)(bflag*8 + nh)*L0 + l)*HD + c;
            *(bf16x8*)&OutQ[addr] = v;
        } else {
            int part = col / 768;
            int cb = col - part*768;
            int nh = cb / HD;
            int c = cb - nh*HD;
            int b = m / 3200; int r = m - b*3200;   // r = t*400 + rr
            size_t addr = ((size_t)(part*16 + b*8 + nh)*3200 + r)*HD + c;
            *(bf16x8*)&OutKV[addr] = v;
        }
    }
}

// ---------------- 128x128 bf16-A GEMM — proj only (R8 structure, unchanged) --------
__global__ __launch_bounds__(256) void gemm_proj(
    const bf16* __restrict__ A, const bf16* __restrict__ B,
    const float* __restrict__ bias, float* __restrict__ Out,
    int M, int N, int K, int NBN)
{
    __shared__ bf16 sh[2*16384];
    const int tid = threadIdx.x;
    const int lane = tid & 63;
    const int w = tid >> 6;
    const int wr = w >> 1, wc = w & 1;

    const int nwg = gridDim.x;
    const int q_ = nwg >> 3, r_ = nwg & 7;
    const int xcd = blockIdx.x & 7, off = blockIdx.x >> 3;
    const int swz = (xcd < r_ ? xcd*(q_+1) : r_*(q_+1) + (xcd - r_)*q_) + off;
    const long bn = swz % NBN, bm = swz / NBN;

    f32x4 acc[4][4];
#pragma unroll
    for (int i = 0; i < 4; ++i)
#pragma unroll
        for (int j = 0; j < 4; ++j) acc[i][j] = (f32x4){0.f,0.f,0.f,0.f};

    const int trow = tid >> 3;
    const int tchunk = (tid & 7) ^ (trow & 7);
    const bf16* Ag = A + (bm*128 + trow)*(long)K + tchunk*8;
    const bf16* Bg = B + (bn*128 + trow)*(long)K + tchunk*8;

    const int arow = lane & 15;
    const int g8 = (lane >> 4) * 8;
    const int aswz = (arow & 7) * 8;

    auto stage = [&](int buf, int kt) {
        bf16* ldsA = sh + buf*16384;
        bf16* ldsB = sh + buf*16384 + 8192;
#pragma unroll
        for (int s = 0; s < 4; ++s) {
            __builtin_amdgcn_global_load_lds(GPTR(Ag + (long)kt*64 + (long)s*32*K),
                                             LPTR(ldsA + s*2048 + tid*8), 16, 0, 0);
            __builtin_amdgcn_global_load_lds(GPTR(Bg + (long)kt*64 + (long)s*32*K),
                                             LPTR(ldsB + s*2048 + tid*8), 16, 0, 0);
        }
    };
    auto compute = [&](int buf) {
        const bf16* ldsA = sh + buf*16384;
        const bf16* ldsB = sh + buf*16384 + 8192;
#pragma unroll
        for (int kk = 0; kk < 2; ++kk) {
            bf16x8 af[4], bfr[4];
#pragma unroll
            for (int i = 0; i < 4; ++i)
                af[i] = *(const bf16x8*)&ldsA[(wr*64 + i*16 + arow)*64 + ((kk*32 + g8) ^ aswz)];
#pragma unroll
            for (int j = 0; j < 4; ++j)
                bfr[j] = *(const bf16x8*)&ldsB[(wc*64 + j*16 + arow)*64 + ((kk*32 + g8) ^ aswz)];
            __builtin_amdgcn_s_setprio(1);
#pragma unroll
            for (int i = 0; i < 4; ++i)
#pragma unroll
                for (int j = 0; j < 4; ++j)
                    acc[i][j] = __builtin_amdgcn_mfma_f32_16x16x32_bf16(af[i], bfr[j], acc[i][j], 0, 0, 0);
            __builtin_amdgcn_s_setprio(0);
        }
    };

    const int nkt = K / 64;
    stage(0, 0);
    for (int kt = 0; kt < nkt; ++kt) {
        if (kt + 1 < nkt) {
            stage((kt + 1) & 1, kt + 1);
            asm volatile("s_waitcnt vmcnt(8)" ::: "memory");
        } else {
            asm volatile("s_waitcnt vmcnt(0)" ::: "memory");
        }
        __builtin_amdgcn_s_barrier();
        __builtin_amdgcn_sched_barrier(0);
        compute(kt & 1);
        __builtin_amdgcn_sched_barrier(0);
        __builtin_amdgcn_s_barrier();
    }

#pragma unroll
    for (int j = 0; j < 4; ++j) {
        const int col = (int)bn*128 + wc*64 + j*16 + (lane & 15);
        const float bcol = bias[col];
#pragma unroll
        for (int i = 0; i < 4; ++i) {
            int row0 = (int)bm*128 + wr*64 + i*16 + ((lane>>4)<<2);
#pragma unroll
            for (int r = 0; r < 4; ++r)
                Out[(size_t)(row0 + r)*N + col] = acc[i][j][r] + bcol;
        }
    }
}

// ---------------- merged depthwise conv3d: q-path + kv-path in one dispatch --------
__global__ __launch_bounds__(256) void dwconv_all(
    const bf16* __restrict__ qin, const bf16* __restrict__ kv,
    const float* __restrict__ wq, const float* __restrict__ wk,
    const float* __restrict__ wv, bf16* __restrict__ qout,
    bf16* __restrict__ kout, bf16* __restrict__ vtout)
{
    __shared__ float lw[27*HD];
    const int blk = blockIdx.x;
    if (blk < 588) {
        for (int i = threadIdx.x; i < 27*HD; i += 256) {
            int c = i / 27, tap = i % 27;
            lw[tap*HD + c] = wq[i];
        }
        __syncthreads();
        int idx = blk*256 + threadIdx.x;
        if (idx >= 16*HP_Q*WP_Q*12) return;
        int c8 = idx % 12;
        int p = idx / 12;
        int xo = p % WP_Q;
        int yo = (p / WP_Q) % HP_Q;
        int bh = p / (WP_Q*HP_Q);
        const bf16* ip = qin + (size_t)bh * L0 * HD + c8*8;

        float acc[T0][8];
#pragma unroll
        for (int t = 0; t < T0; ++t)
#pragma unroll
            for (int j = 0; j < 8; ++j) acc[t][j] = 0.f;

#pragma unroll
        for (int dy = 0; dy < 3; ++dy) {
            int y = yo*2 + dy - 1;
            if ((unsigned)y >= (unsigned)H0) continue;
#pragma unroll
            for (int dx = 0; dx < 3; ++dx) {
                int x = xo*2 + dx - 1;
                if ((unsigned)x >= (unsigned)W0) continue;
                float wreg[3][8];
#pragma unroll
                for (int dt = 0; dt < 3; ++dt)
#pragma unroll
                    for (int j = 0; j < 8; ++j)
                        wreg[dt][j] = lw[(dt*9 + dy*3 + dx)*HD + c8*8 + j];
                const bf16* colp = ip + ((size_t)(y*W0 + x))*HD;
#pragma unroll
                for (int t = 0; t < T0; ++t) {
                    bf16x8 v = *(const bf16x8*)(colp + (size_t)t*H0*W0*HD);
                    float f[8];
#pragma unroll
                    for (int j = 0; j < 8; ++j) f[j] = (float)v[j];
#pragma unroll
                    for (int dt = 0; dt < 3; ++dt) {
                        int to = t - dt + 1;
                        if (to < 0 || to >= T0) continue;
#pragma unroll
                        for (int j = 0; j < 8; ++j)
                            acc[to][j] += wreg[dt][j] * f[j];
                    }
                }
            }
        }

#pragma unroll
        for (int to = 0; to < T0; ++to) {
            int l = (to*HP_Q + yo)*WP_Q + xo;
            bf16x8 ov;
#pragma unroll
            for (int j = 0; j < 8; ++j) ov[j] = (bf16)acc[to][j];
            *(bf16x8*)&qout[((size_t)bh*LQ + l)*HD + c8*8] = ov;
        }
        return;
    }

    const int kb = blk - 588;          // 0..79
    const int seg = kb / 40;
    const int lb  = kb % 40;
    const float* w = seg ? wv : wk;
    const bf16* in = kv + (size_t)seg * 16 * 3200 * HD;
    for (int i = threadIdx.x; i < 27*HD; i += 256) {
        int c = i / 27, tap = i % 27;
        lw[tap*HD + c] = w[i];
    }
    __syncthreads();

    if (lb >= 37) {   // pad-zero blocks
        int pid = (lb - 37)*256 + threadIdx.x;
        if (seg == 0) {
            for (int e = pid; e < 16*24*96; e += 768) {
                int bh = e / (24*96); int rem = e - bh*24*96;
                int l = LK + rem / 96; int c = rem % 96;
                kout[((size_t)bh*LKP + l)*HD + c] = (bf16)0.f;
            }
        } else {
            for (int e = pid; e < 16*96*24; e += 768) {
                int bh = e / (96*24); int rem = e - bh*96*24;
                int c = rem / 24; int l = LK + rem % 24;
                vtout[((size_t)bh*HD + c)*LKP + l] = (bf16)0.f;
            }
        }
        return;
    }

    int idx = lb*256 + threadIdx.x;
    if (idx >= 16*HP_K*WP_K*12) return;
    int c8 = idx % 12;
    int p = idx / 12;
    int xo = p % WP_K;
    int yo = (p / WP_K) % HP_K;
    int bh = p / (WP_K*HP_K);
    const bf16* ip = in + (size_t)bh * 3200 * HD + c8*8;

    float acc[T0][8];
#pragma unroll
    for (int t = 0; t < T0; ++t)
#pragma unroll
        for (int j = 0; j < 8; ++j) acc[t][j] = 0.f;

#pragma unroll
    for (int dy = 0; dy < 3; ++dy) {
        int yi = 3*yo + dy - 1;
        if ((unsigned)yi >= (unsigned)NYC) continue;
#pragma unroll
        for (int dx = 0; dx < 3; ++dx) {
            int xi = 3*xo + dx - 1;
            if ((unsigned)xi >= (unsigned)NYC) continue;
            float wreg[3][8];
#pragma unroll
            for (int dt = 0; dt < 3; ++dt)
#pragma unroll
                for (int j = 0; j < 8; ++j)
                    wreg[dt][j] = lw[(dt*9 + dy*3 + dx)*HD + c8*8 + j];
            const bf16* colp = ip + ((size_t)(yi*NYC + xi))*HD;
#pragma unroll
            for (int t = 0; t < T0; ++t) {
                bf16x8 v = *(const bf16x8*)(colp + (size_t)t*400*HD);
                float f[8];
#pragma unroll
                for (int j = 0; j < 8; ++j) f[j] = (float)v[j];
#pragma unroll
                for (int dt = 0; dt < 3; ++dt) {
                    int to = t - dt + 1;
                    if (to < 0 || to >= T0) continue;
#pragma unroll
                    for (int j = 0; j < 8; ++j)
                        acc[to][j] += wreg[dt][j] * f[j];
                }
            }
        }
    }

#pragma unroll
    for (int to = 0; to < T0; ++to) {
        int l = (to*HP_K + yo)*WP_K + xo;
        if (seg == 1) {
#pragma unroll
            for (int j = 0; j < 8; ++j)
                vtout[((size_t)bh*HD + c8*8 + j)*LKP + l] = (bf16)acc[to][j];
        } else {
            bf16x8 ov;
#pragma unroll
            for (int j = 0; j < 8; ++j) ov[j] = (bf16)acc[to][j];
            *(bf16x8*)&kout[((size_t)bh*LKP + l)*HD + c8*8] = ov;
        }
    }
}

// ---------------- MFMA attention: block = (b,h) x 64 q rows, wave = 16 q rows -------
__global__ __launch_bounds__(256) void attn_mfma(
    const bf16* __restrict__ q, const bf16* __restrict__ k,
    const bf16* __restrict__ vt, bf16* __restrict__ out)
{
    const int tid = threadIdx.x;
    const int lane = tid & 63;
    const int w = tid >> 6;
    const int col = lane & 15;
    const int g = lane >> 4;
    const int blk = blockIdx.x;
    const int qblk = blk % (LQ/64);
    const int bh = blk / (LQ/64);
    const int q0 = qblk*64 + w*16;

    const bf16* Qp  = q  + ((size_t)bh*LQ + q0)*HD;
    const bf16* Kp  = k  + (size_t)bh*LKP*HD;
    const bf16* VTp = vt + (size_t)bh*HD*LKP;

    bf16x8 qf[3];
#pragma unroll
    for (int c = 0; c < 3; ++c)
        qf[c] = *(const bf16x8*)&Qp[(size_t)col*HD + c*32 + g*8];

    f32x4 o[6];
#pragma unroll
    for (int t = 0; t < 6; ++t) o[t] = (f32x4){0.f,0.f,0.f,0.f};
    float lsum = 0.f;

    for (int kc = 0; kc < LKP/32; ++kc) {
        const int kvb = kc*32;
        uint32_t P[2][2];
#pragma unroll
        for (int s = 0; s < 2; ++s) {
            f32x4 acc = (f32x4){0.f,0.f,0.f,0.f};
#pragma unroll
            for (int c = 0; c < 3; ++c) {
                bf16x8 kf = *(const bf16x8*)&Kp[(size_t)(kvb + s*16 + col)*HD + c*32 + g*8];
                acc = __builtin_amdgcn_mfma_f32_16x16x32_bf16(kf, qf[c], acc, 0, 0, 0);
            }
            bf16x4 pb;
#pragma unroll
            for (int r = 0; r < 4; ++r) {
                int kv = kvb + s*16 + g*4 + r;
                float p = (kv < LK) ? __expf(acc[r]*SCALE) : 0.f;
                lsum += p;
                pb[r] = (bf16)p;
            }
            union { bf16x4 v; uint32_t u[2]; } pk; pk.v = pb;
            P[s][0] = pk.u[0]; P[s][1] = pk.u[1];
        }
        uint32_t sa0 = (g < 2) ? P[1][0] : P[0][0];
        uint32_t sa1 = (g < 2) ? P[1][1] : P[0][1];
        uint32_t tb0 = (g < 2) ? P[0][0] : P[1][0];
        uint32_t tb1 = (g < 2) ? P[0][1] : P[1][1];
        uint32_t R32_0 = (uint32_t)__shfl_xor((int)sa0, 32);
        uint32_t R32_1 = (uint32_t)__shfl_xor((int)sa1, 32);
        uint32_t R48_0 = (uint32_t)__shfl_xor((int)sa0, 48);
        uint32_t R48_1 = (uint32_t)__shfl_xor((int)sa1, 48);
        uint32_t R16_0 = (uint32_t)__shfl_xor((int)tb0, 16);
        uint32_t R16_1 = (uint32_t)__shfl_xor((int)tb1, 16);
        union { uint32_t u[4]; bf16x8 v; } pf;
        pf.u[0] = (g == 0) ? P[0][0] : (g == 1) ? R48_0 : (g == 2) ? R32_0 : R16_0;
        pf.u[1] = (g == 0) ? P[0][1] : (g == 1) ? R48_1 : (g == 2) ? R32_1 : R16_1;
        pf.u[2] = (g == 0) ? R16_0 : (g == 1) ? R32_0 : (g == 2) ? R48_0 : P[1][0];
        pf.u[3] = (g == 0) ? R16_1 : (g == 1) ? R32_1 : (g == 2) ? R48_1 : P[1][1];
#pragma unroll
        for (int t = 0; t < 6; ++t) {
            bf16x8 vf = *(const bf16x8*)&VTp[(size_t)(t*16 + col)*LKP + kvb + g*8];
            o[t] = __builtin_amdgcn_mfma_f32_16x16x32_bf16(vf, pf.v, o[t], 0, 0, 0);
        }
    }

    lsum += __shfl_xor(lsum, 16);
    lsum += __shfl_xor(lsum, 32);
    float inv = 1.f / lsum;

    const int b = bh >> 3, nh = bh & 7;
    size_t obase = ((size_t)b*LQ + q0 + col)*CDIM + (size_t)nh*HD;
#pragma unroll
    for (int t = 0; t < 6; ++t) {
        bf16x4 qres = *(const bf16x4*)&Qp[(size_t)col*HD + t*16 + g*4];
        bf16x4 ov;
#pragma unroll
        for (int r = 0; r < 4; ++r)
            ov[r] = (bf16)(o[t][r]*inv + (float)qres[r]);
        *(bf16x4*)&out[obase + t*16 + g*4] = ov;
    }
}

extern "C" void kernel_launch(void* const* d_in, const int* in_sizes, int n_in,
                              void* d_out, int out_size, void* d_ws, size_t ws_size,
                              hipStream_t stream) {
    const float* x      = (const float*)d_in[0];
    const float* qkv_w  = (const float*)d_in[1];
    const float* qkv_b  = (const float*)d_in[2];
    const float* proj_w = (const float*)d_in[3];
    const float* proj_b = (const float*)d_in[4];
    const float* pq_w   = (const float*)d_in[5];
    const float* pk_w   = (const float*)d_in[6];
    const float* pv_w   = (const float*)d_in[7];

    uint8_t* ws = (uint8_t*)d_ws;
    bf16* x_bf     = (bf16*)(ws);                  // 77,070,336 B  [2][L0][768]
    bf16* qg_out   = (bf16*)(ws +  77070336);      // 77,070,336 B  [16][L0][96] (GELU'd Q)
    bf16* kv_c     = (bf16*)(ws + 154140672);      // 19,660,800 B  [2][16][3200][96]
    bf16* wqkv_bf  = (bf16*)(ws + 173801472);      // 3,538,944 B
    bf16* wproj_bf = (bf16*)(ws + 177340416);      // 1,179,648 B
    bf16* q_bf     = (bf16*)(ws + 178520064);      // 19,267,584 B  [16][6272][96]
    bf16* k_bf     = (bf16*)(ws + 197787648);      // 1,277,952 B   [16][416][96]
    bf16* vt_bf    = (bf16*)(ws + 199065600);      // 1,277,952 B   [16][96][416]
    bf16* attn_o   = (bf16*)(ws + 200343552);      // 19,267,584 B -> end 219,611,136

    cvt_all<<<2560, 256, 0, stream>>>((const f4*)x, (const f4*)qkv_w, (const f4*)proj_w,
                                      (bf16x4*)x_bf, (bf16x4*)wqkv_bf, (bf16x4*)wproj_bf);

    // merged Q + KV GEMM (2952 blocks, BK=32 dbuf, 4 blocks/CU)
    gemm_qkv<<<NBQ + NBKV, 256, 0, stream>>>(x_bf, wqkv_bf, qkv_b, qg_out, kv_c);

    // merged convs (q + k + v + pad-zeroing, one dispatch)
    dwconv_all<<<668, 256, 0, stream>>>(qg_out, kv_c, pq_w, pk_w, pv_w,
                                        q_bf, k_bf, vt_bf);

    attn_mfma<<<16*(LQ/64), 256, 0, stream>>>(q_bf, k_bf, vt_bf, attn_o);

    gemm_proj<<<6*98, 256, 0, stream>>>(
        attn_o, wproj_bf, proj_b, (float*)d_out, 12544, 768, 768, 6);
}

// Round 15
// 281.886 us; speedup vs baseline: 1.0508x; 1.0508x over previous
//
#include <hip/hip_runtime.h>
#include <cstdint>

#define NH 8
#define HD 96
#define CDIM 768
#define BQ 2
#define T0 8
#define H0 56
#define W0 56
#define L0 (T0*H0*W0)     // 25088
#define HP_Q 28
#define WP_Q 28
#define LQ (T0*HP_Q*WP_Q) // 6272
#define HP_K 7
#define WP_K 7
#define LK (T0*HP_K*WP_K) // 392
#define LKP 416           // kv padded to multiple of 32
#define SCALE 0.10206207261596577f
#define NYC 20
#define MKV 6400          // 2*8*400 gathered kv rows (50 x 128)
#define NBQ 2352          // Q-gemm blocks: 392 bm x 6 bn
#define NBKV 600          // KV-gemm blocks: 50 bm x 12 bn

typedef __bf16 bf16;
typedef bf16 bf16x4 __attribute__((ext_vector_type(4)));
typedef bf16 bf16x8 __attribute__((ext_vector_type(8)));
typedef float f32x4 __attribute__((ext_vector_type(4)));
typedef float f4 __attribute__((ext_vector_type(4)));

#define GPTR(x) ((const __attribute__((address_space(1))) void*)(x))
#define LPTR(x) ((__attribute__((address_space(3))) void*)(x))

// fast erf-GELU: A&S 7.1.27 rational erf approx, |err(erf)| <= 5e-4 (<< bf16 rounding)
__device__ __forceinline__ float fast_gelu(float x) {
    float z = __builtin_fabsf(x) * 0.7071067811865476f;
    float p = 1.f + z*(0.278393f + z*(0.230389f + z*(0.000972f + z*0.078108f)));
    p = p * p;
    p = p * p;
    float e = 1.f - __builtin_amdgcn_rcpf(p);   // erf(|x|/sqrt2)
    float erfv = (x < 0.f) ? -e : e;
    return 0.5f * x * (1.f + erfv);
}

// ---------------- fused fp32 -> bf16 conversion (x, qkv_w, proj_w) -----------------
#define NX4 9633792
#define NW4 442368
#define NP4 147456
__global__ void cvt_all(const f4* __restrict__ x, const f4* __restrict__ wq,
                        const f4* __restrict__ wp, bf16x4* __restrict__ xo,
                        bf16x4* __restrict__ wqo, bf16x4* __restrict__ wpo) {
    const long total = (long)NX4 + NW4 + NP4;
    long stride = (long)gridDim.x * blockDim.x;
    for (long i = (long)blockIdx.x * blockDim.x + threadIdx.x; i < total; i += stride) {
        f4 v; bf16x4* o;
        if (i < NX4)            { v = x[i];              o = xo + i; }
        else if (i < NX4 + NW4) { v = wq[i - NX4];       o = wqo + (i - NX4); }
        else                    { v = wp[i - NX4 - NW4]; o = wpo + (i - NX4 - NW4); }
        bf16x4 t;
        t[0] = (bf16)v[0]; t[1] = (bf16)v[1]; t[2] = (bf16)v[2]; t[3] = (bf16)v[3];
        *o = t;
    }
}

// map compact grid index (0..19) -> original spatial coord (y or x)
__device__ __forceinline__ int cmap(int i) {
    return ((i + 1) / 3) * 8 + (i + 1) % 3 - 1;
}

// ======== merged Q + KV 128x128 GEMM, bf16 A via global_load_lds (R13/R8 config) ===
// blocks [0, NBQ):        Q.  M=50176, N=768 (6 bn), GELU, scatter [16][L0][96]
// blocks [NBQ, NBQ+NBKV): KV. M=6400 gathered rows, N=1536 (12 bn), GELU,
//                             compact store [part][b*8+nh][t*400+rr][96]
// BK=64 dbuf (64KB), T1 XCD swizzle, T2 source-side chunk swizzle, counted vmcnt(8),
// two-barrier K-loop — the measured optimum of this kernel family (R6-R14 bracket).
__global__ __launch_bounds__(256) void gemm_qkv(
    const bf16* __restrict__ A, const bf16* __restrict__ Wq,
    const float* __restrict__ bias_q, bf16* __restrict__ OutQ,
    bf16* __restrict__ OutKV)
{
    __shared__ bf16 sh[2*16384];     // [buf][A:8192|B:8192] elements = 64 KiB
    const int tid = threadIdx.x;
    const int lane = tid & 63;
    const int w = tid >> 6;
    const int wr = w >> 1, wc = w & 1;
    const int K = 768;

    // T1: XCD-chunked bijective swizzle over the merged grid (2952 = 8*369)
    const int nwg = gridDim.x;
    const int q_ = nwg >> 3, r_ = nwg & 7;
    const int xcd = blockIdx.x & 7, off = blockIdx.x >> 3;
    const int swz = (xcd < r_ ? xcd*(q_+1) : r_*(q_+1) + (xcd - r_)*q_) + off;

    const bool isQ = swz < NBQ;
    const int idx = isQ ? swz : swz - NBQ;
    const int NBN = isQ ? 6 : 12;
    const long bm = idx / NBN, bn = idx % NBN;
    const bf16* B = isQ ? Wq : Wq + (size_t)768*768;
    const float* bias = isQ ? bias_q : bias_q + 768;

    f32x4 acc[4][4];
#pragma unroll
    for (int i = 0; i < 4; ++i)
#pragma unroll
        for (int j = 0; j < 4; ++j) acc[i][j] = (f32x4){0.f,0.f,0.f,0.f};

    const int trow = tid >> 3;                       // 0..31
    const int tchunk = (tid & 7) ^ (trow & 7);       // inverse swizzle on SOURCE

    long aoff[4];
#pragma unroll
    for (int s = 0; s < 4; ++s) {
        int rA = (int)bm*128 + s*32 + trow;
        if (!isQ) {
            int b = rA / 3200; int r = rA - b*3200;
            int t = r / 400;  int rr = r - t*400;
            int yi = rr / NYC, xi = rr - yi*NYC;
            aoff[s] = ((long)b*L0 + (t*H0 + cmap(yi))*W0 + cmap(xi)) * (long)K;
        } else {
            aoff[s] = (long)rA * K;
        }
    }
    const bf16* Bg = B + (bn*128 + trow)*(long)K + tchunk*8;

    const int arow = lane & 15;
    const int g8 = (lane >> 4) * 8;
    const int aswz = (arow & 7) * 8;                 // element-XOR for ds_read

    auto stage = [&](int buf, int kt) {
        bf16* ldsA = sh + buf*16384;
        bf16* ldsB = sh + buf*16384 + 8192;
#pragma unroll
        for (int s = 0; s < 4; ++s) {
            __builtin_amdgcn_global_load_lds(GPTR(A + aoff[s] + kt*64 + tchunk*8),
                                             LPTR(ldsA + s*2048 + tid*8), 16, 0, 0);
            __builtin_amdgcn_global_load_lds(GPTR(Bg + (long)kt*64 + (long)s*32*K),
                                             LPTR(ldsB + s*2048 + tid*8), 16, 0, 0);
        }
    };
    auto compute = [&](int buf) {
        const bf16* ldsA = sh + buf*16384;
        const bf16* ldsB = sh + buf*16384 + 8192;
#pragma unroll
        for (int kk = 0; kk < 2; ++kk) {
            bf16x8 af[4], bfr[4];
#pragma unroll
            for (int i = 0; i < 4; ++i)
                af[i] = *(const bf16x8*)&ldsA[(wr*64 + i*16 + arow)*64 + ((kk*32 + g8) ^ aswz)];
#pragma unroll
            for (int j = 0; j < 4; ++j)
                bfr[j] = *(const bf16x8*)&ldsB[(wc*64 + j*16 + arow)*64 + ((kk*32 + g8) ^ aswz)];
            __builtin_amdgcn_s_setprio(1);
#pragma unroll
            for (int i = 0; i < 4; ++i)
#pragma unroll
                for (int j = 0; j < 4; ++j)
                    acc[i][j] = __builtin_amdgcn_mfma_f32_16x16x32_bf16(af[i], bfr[j], acc[i][j], 0, 0, 0);
            __builtin_amdgcn_s_setprio(0);
        }
    };

    const int nkt = K / 64;   // 12
    stage(0, 0);
    for (int kt = 0; kt < nkt; ++kt) {
        if (kt + 1 < nkt) {
            stage((kt + 1) & 1, kt + 1);
            asm volatile("s_waitcnt vmcnt(8)" ::: "memory");   // kt's 8 loads landed
        } else {
            asm volatile("s_waitcnt vmcnt(0)" ::: "memory");
        }
        __builtin_amdgcn_s_barrier();
        __builtin_amdgcn_sched_barrier(0);
        compute(kt & 1);
        __builtin_amdgcn_sched_barrier(0);
        __builtin_amdgcn_s_barrier();
    }

    // ---------------- epilogue: LDS transpose + GELU + coalesced bf16x8 stores ------
    __syncthreads();
    bf16* tls = sh;                        // 128 x 136 bf16 = 34.8 KB
#pragma unroll
    for (int j = 0; j < 4; ++j) {
        const int colb = (int)bn*128 + wc*64 + j*16;
        const int lcol = wc*64 + j*16 + (lane & 15);
        const float bcol = bias[colb + (lane & 15)];
#pragma unroll
        for (int i = 0; i < 4; ++i) {
            int lrow0 = wr*64 + i*16 + ((lane>>4)<<2);
#pragma unroll
            for (int r = 0; r < 4; ++r)
                tls[(lrow0 + r)*136 + lcol] = (bf16)fast_gelu(acc[i][j][r] + bcol);
        }
    }
    __syncthreads();
#pragma unroll
    for (int it = 0; it < 8; ++it) {
        int idx2 = it*256 + tid;
        int mloc = idx2 >> 4;
        int ck = idx2 & 15;
        bf16x8 v = *(const bf16x8*)&tls[mloc*136 + ck*8];
        int m = (int)bm*128 + mloc;
        int col = (int)bn*128 + ck*8;
        if (isQ) {
            int nh = col / HD;
            int c = col - nh*HD;
            int bflag = m >= L0;              // M = 2*L0
            int l = m - (bflag ? L0 : 0);
            size_t addr = ((size_t)(bflag*8 + nh)*L0 + l)*HD + c;
            *(bf16x8*)&OutQ[addr] = v;
        } else {
            int part = col / 768;
            int cb = col - part*768;
            int nh = cb / HD;
            int c = cb - nh*HD;
            int b = m / 3200; int r = m - b*3200;   // r = t*400 + rr
            size_t addr = ((size_t)(part*16 + b*8 + nh)*3200 + r)*HD + c;
            *(bf16x8*)&OutKV[addr] = v;
        }
    }
}

// ---------------- 128x128 bf16-A GEMM — proj only (R8 structure, unchanged) --------
__global__ __launch_bounds__(256) void gemm_proj(
    const bf16* __restrict__ A, const bf16* __restrict__ B,
    const float* __restrict__ bias, float* __restrict__ Out,
    int M, int N, int K, int NBN)
{
    __shared__ bf16 sh[2*16384];
    const int tid = threadIdx.x;
    const int lane = tid & 63;
    const int w = tid >> 6;
    const int wr = w >> 1, wc = w & 1;

    const int nwg = gridDim.x;
    const int q_ = nwg >> 3, r_ = nwg & 7;
    const int xcd = blockIdx.x & 7, off = blockIdx.x >> 3;
    const int swz = (xcd < r_ ? xcd*(q_+1) : r_*(q_+1) + (xcd - r_)*q_) + off;
    const long bn = swz % NBN, bm = swz / NBN;

    f32x4 acc[4][4];
#pragma unroll
    for (int i = 0; i < 4; ++i)
#pragma unroll
        for (int j = 0; j < 4; ++j) acc[i][j] = (f32x4){0.f,0.f,0.f,0.f};

    const int trow = tid >> 3;
    const int tchunk = (tid & 7) ^ (trow & 7);
    const bf16* Ag = A + (bm*128 + trow)*(long)K + tchunk*8;
    const bf16* Bg = B + (bn*128 + trow)*(long)K + tchunk*8;

    const int arow = lane & 15;
    const int g8 = (lane >> 4) * 8;
    const int aswz = (arow & 7) * 8;

    auto stage = [&](int buf, int kt) {
        bf16* ldsA = sh + buf*16384;
        bf16* ldsB = sh + buf*16384 + 8192;
#pragma unroll
        for (int s = 0; s < 4; ++s) {
            __builtin_amdgcn_global_load_lds(GPTR(Ag + (long)kt*64 + (long)s*32*K),
                                             LPTR(ldsA + s*2048 + tid*8), 16, 0, 0);
            __builtin_amdgcn_global_load_lds(GPTR(Bg + (long)kt*64 + (long)s*32*K),
                                             LPTR(ldsB + s*2048 + tid*8), 16, 0, 0);
        }
    };
    auto compute = [&](int buf) {
        const bf16* ldsA = sh + buf*16384;
        const bf16* ldsB = sh + buf*16384 + 8192;
#pragma unroll
        for (int kk = 0; kk < 2; ++kk) {
            bf16x8 af[4], bfr[4];
#pragma unroll
            for (int i = 0; i < 4; ++i)
                af[i] = *(const bf16x8*)&ldsA[(wr*64 + i*16 + arow)*64 + ((kk*32 + g8) ^ aswz)];
#pragma unroll
            for (int j = 0; j < 4; ++j)
                bfr[j] = *(const bf16x8*)&ldsB[(wc*64 + j*16 + arow)*64 + ((kk*32 + g8) ^ aswz)];
            __builtin_amdgcn_s_setprio(1);
#pragma unroll
            for (int i = 0; i < 4; ++i)
#pragma unroll
                for (int j = 0; j < 4; ++j)
                    acc[i][j] = __builtin_amdgcn_mfma_f32_16x16x32_bf16(af[i], bfr[j], acc[i][j], 0, 0, 0);
            __builtin_amdgcn_s_setprio(0);
        }
    };

    const int nkt = K / 64;
    stage(0, 0);
    for (int kt = 0; kt < nkt; ++kt) {
        if (kt + 1 < nkt) {
            stage((kt + 1) & 1, kt + 1);
            asm volatile("s_waitcnt vmcnt(8)" ::: "memory");
        } else {
            asm volatile("s_waitcnt vmcnt(0)" ::: "memory");
        }
        __builtin_amdgcn_s_barrier();
        __builtin_amdgcn_sched_barrier(0);
        compute(kt & 1);
        __builtin_amdgcn_sched_barrier(0);
        __builtin_amdgcn_s_barrier();
    }

#pragma unroll
    for (int j = 0; j < 4; ++j) {
        const int col = (int)bn*128 + wc*64 + j*16 + (lane & 15);
        const float bcol = bias[col];
#pragma unroll
        for (int i = 0; i < 4; ++i) {
            int row0 = (int)bm*128 + wr*64 + i*16 + ((lane>>4)<<2);
#pragma unroll
            for (int r = 0; r < 4; ++r)
                Out[(size_t)(row0 + r)*N + col] = acc[i][j][r] + bcol;
        }
    }
}

// ---------------- merged depthwise conv3d: q-path + kv-path in one dispatch --------
__global__ __launch_bounds__(256) void dwconv_all(
    const bf16* __restrict__ qin, const bf16* __restrict__ kv,
    const float* __restrict__ wq, const float* __restrict__ wk,
    const float* __restrict__ wv, bf16* __restrict__ qout,
    bf16* __restrict__ kout, bf16* __restrict__ vtout)
{
    __shared__ float lw[27*HD];
    const int blk = blockIdx.x;
    if (blk < 588) {
        for (int i = threadIdx.x; i < 27*HD; i += 256) {
            int c = i / 27, tap = i % 27;
            lw[tap*HD + c] = wq[i];
        }
        __syncthreads();
        int idx = blk*256 + threadIdx.x;
        if (idx >= 16*HP_Q*WP_Q*12) return;
        int c8 = idx % 12;
        int p = idx / 12;
        int xo = p % WP_Q;
        int yo = (p / WP_Q) % HP_Q;
        int bh = p / (WP_Q*HP_Q);
        const bf16* ip = qin + (size_t)bh * L0 * HD + c8*8;

        float acc[T0][8];
#pragma unroll
        for (int t = 0; t < T0; ++t)
#pragma unroll
            for (int j = 0; j < 8; ++j) acc[t][j] = 0.f;

#pragma unroll
        for (int dy = 0; dy < 3; ++dy) {
            int y = yo*2 + dy - 1;
            if ((unsigned)y >= (unsigned)H0) continue;
#pragma unroll
            for (int dx = 0; dx < 3; ++dx) {
                int x = xo*2 + dx - 1;
                if ((unsigned)x >= (unsigned)W0) continue;
                float wreg[3][8];
#pragma unroll
                for (int dt = 0; dt < 3; ++dt)
#pragma unroll
                    for (int j = 0; j < 8; ++j)
                        wreg[dt][j] = lw[(dt*9 + dy*3 + dx)*HD + c8*8 + j];
                const bf16* colp = ip + ((size_t)(y*W0 + x))*HD;
#pragma unroll
                for (int t = 0; t < T0; ++t) {
                    bf16x8 v = *(const bf16x8*)(colp + (size_t)t*H0*W0*HD);
                    float f[8];
#pragma unroll
                    for (int j = 0; j < 8; ++j) f[j] = (float)v[j];
#pragma unroll
                    for (int dt = 0; dt < 3; ++dt) {
                        int to = t - dt + 1;
                        if (to < 0 || to >= T0) continue;
#pragma unroll
                        for (int j = 0; j < 8; ++j)
                            acc[to][j] += wreg[dt][j] * f[j];
                    }
                }
            }
        }

#pragma unroll
        for (int to = 0; to < T0; ++to) {
            int l = (to*HP_Q + yo)*WP_Q + xo;
            bf16x8 ov;
#pragma unroll
            for (int j = 0; j < 8; ++j) ov[j] = (bf16)acc[to][j];
            *(bf16x8*)&qout[((size_t)bh*LQ + l)*HD + c8*8] = ov;
        }
        return;
    }

    const int kb = blk - 588;          // 0..79
    const int seg = kb / 40;
    const int lb  = kb % 40;
    const float* w = seg ? wv : wk;
    const bf16* in = kv + (size_t)seg * 16 * 3200 * HD;
    for (int i = threadIdx.x; i < 27*HD; i += 256) {
        int c = i / 27, tap = i % 27;
        lw[tap*HD + c] = w[i];
    }
    __syncthreads();

    if (lb >= 37) {   // pad-zero blocks
        int pid = (lb - 37)*256 + threadIdx.x;
        if (seg == 0) {
            for (int e = pid; e < 16*24*96; e += 768) {
                int bh = e / (24*96); int rem = e - bh*24*96;
                int l = LK + rem / 96; int c = rem % 96;
                kout[((size_t)bh*LKP + l)*HD + c] = (bf16)0.f;
            }
        } else {
            for (int e = pid; e < 16*96*24; e += 768) {
                int bh = e / (96*24); int rem = e - bh*96*24;
                int c = rem / 24; int l = LK + rem % 24;
                vtout[((size_t)bh*HD + c)*LKP + l] = (bf16)0.f;
            }
        }
        return;
    }

    int idx = lb*256 + threadIdx.x;
    if (idx >= 16*HP_K*WP_K*12) return;
    int c8 = idx % 12;
    int p = idx / 12;
    int xo = p % WP_K;
    int yo = (p / WP_K) % HP_K;
    int bh = p / (WP_K*HP_K);
    const bf16* ip = in + (size_t)bh * 3200 * HD + c8*8;

    float acc[T0][8];
#pragma unroll
    for (int t = 0; t < T0; ++t)
#pragma unroll
        for (int j = 0; j < 8; ++j) acc[t][j] = 0.f;

#pragma unroll
    for (int dy = 0; dy < 3; ++dy) {
        int yi = 3*yo + dy - 1;
        if ((unsigned)yi >= (unsigned)NYC) continue;
#pragma unroll
        for (int dx = 0; dx < 3; ++dx) {
            int xi = 3*xo + dx - 1;
            if ((unsigned)xi >= (unsigned)NYC) continue;
            float wreg[3][8];
#pragma unroll
            for (int dt = 0; dt < 3; ++dt)
#pragma unroll
                for (int j = 0; j < 8; ++j)
                    wreg[dt][j] = lw[(dt*9 + dy*3 + dx)*HD + c8*8 + j];
            const bf16* colp = ip + ((size_t)(yi*NYC + xi))*HD;
#pragma unroll
            for (int t = 0; t < T0; ++t) {
                bf16x8 v = *(const bf16x8*)(colp + (size_t)t*400*HD);
                float f[8];
#pragma unroll
                for (int j = 0; j < 8; ++j) f[j] = (float)v[j];
#pragma unroll
                for (int dt = 0; dt < 3; ++dt) {
                    int to = t - dt + 1;
                    if (to < 0 || to >= T0) continue;
#pragma unroll
                    for (int j = 0; j < 8; ++j)
                        acc[to][j] += wreg[dt][j] * f[j];
                }
            }
        }
    }

#pragma unroll
    for (int to = 0; to < T0; ++to) {
        int l = (to*HP_K + yo)*WP_K + xo;
        if (seg == 1) {
#pragma unroll
            for (int j = 0; j < 8; ++j)
                vtout[((size_t)bh*HD + c8*8 + j)*LKP + l] = (bf16)acc[to][j];
        } else {
            bf16x8 ov;
#pragma unroll
            for (int j = 0; j < 8; ++j) ov[j] = (bf16)acc[to][j];
            *(bf16x8*)&kout[((size_t)bh*LKP + l)*HD + c8*8] = ov;
        }
    }
}

// ---------------- MFMA attention: block = (b,h) x 64 q rows, wave = 16 q rows -------
__global__ __launch_bounds__(256) void attn_mfma(
    const bf16* __restrict__ q, const bf16* __restrict__ k,
    const bf16* __restrict__ vt, bf16* __restrict__ out)
{
    const int tid = threadIdx.x;
    const int lane = tid & 63;
    const int w = tid >> 6;
    const int col = lane & 15;
    const int g = lane >> 4;
    const int blk = blockIdx.x;
    const int qblk = blk % (LQ/64);
    const int bh = blk / (LQ/64);
    const int q0 = qblk*64 + w*16;

    const bf16* Qp  = q  + ((size_t)bh*LQ + q0)*HD;
    const bf16* Kp  = k  + (size_t)bh*LKP*HD;
    const bf16* VTp = vt + (size_t)bh*HD*LKP;

    bf16x8 qf[3];
#pragma unroll
    for (int c = 0; c < 3; ++c)
        qf[c] = *(const bf16x8*)&Qp[(size_t)col*HD + c*32 + g*8];

    f32x4 o[6];
#pragma unroll
    for (int t = 0; t < 6; ++t) o[t] = (f32x4){0.f,0.f,0.f,0.f};
    float lsum = 0.f;

    for (int kc = 0; kc < LKP/32; ++kc) {
        const int kvb = kc*32;
        uint32_t P[2][2];
#pragma unroll
        for (int s = 0; s < 2; ++s) {
            f32x4 acc = (f32x4){0.f,0.f,0.f,0.f};
#pragma unroll
            for (int c = 0; c < 3; ++c) {
                bf16x8 kf = *(const bf16x8*)&Kp[(size_t)(kvb + s*16 + col)*HD + c*32 + g*8];
                acc = __builtin_amdgcn_mfma_f32_16x16x32_bf16(kf, qf[c], acc, 0, 0, 0);
            }
            bf16x4 pb;
#pragma unroll
            for (int r = 0; r < 4; ++r) {
                int kv = kvb + s*16 + g*4 + r;
                float p = (kv < LK) ? __expf(acc[r]*SCALE) : 0.f;
                lsum += p;
                pb[r] = (bf16)p;
            }
            union { bf16x4 v; uint32_t u[2]; } pk; pk.v = pb;
            P[s][0] = pk.u[0]; P[s][1] = pk.u[1];
        }
        uint32_t sa0 = (g < 2) ? P[1][0] : P[0][0];
        uint32_t sa1 = (g < 2) ? P[1][1] : P[0][1];
        uint32_t tb0 = (g < 2) ? P[0][0] : P[1][0];
        uint32_t tb1 = (g < 2) ? P[0][1] : P[1][1];
        uint32_t R32_0 = (uint32_t)__shfl_xor((int)sa0, 32);
        uint32_t R32_1 = (uint32_t)__shfl_xor((int)sa1, 32);
        uint32_t R48_0 = (uint32_t)__shfl_xor((int)sa0, 48);
        uint32_t R48_1 = (uint32_t)__shfl_xor((int)sa1, 48);
        uint32_t R16_0 = (uint32_t)__shfl_xor((int)tb0, 16);
        uint32_t R16_1 = (uint32_t)__shfl_xor((int)tb1, 16);
        union { uint32_t u[4]; bf16x8 v; } pf;
        pf.u[0] = (g == 0) ? P[0][0] : (g == 1) ? R48_0 : (g == 2) ? R32_0 : R16_0;
        pf.u[1] = (g == 0) ? P[0][1] : (g == 1) ? R48_1 : (g == 2) ? R32_1 : R16_1;
        pf.u[2] = (g == 0) ? R16_0 : (g == 1) ? R32_0 : (g == 2) ? R48_0 : P[1][0];
        pf.u[3] = (g == 0) ? R16_1 : (g == 1) ? R32_1 : (g == 2) ? R48_1 : P[1][1];
#pragma unroll
        for (int t = 0; t < 6; ++t) {
            bf16x8 vf = *(const bf16x8*)&VTp[(size_t)(t*16 + col)*LKP + kvb + g*8];
            o[t] = __builtin_amdgcn_mfma_f32_16x16x32_bf16(vf, pf.v, o[t], 0, 0, 0);
        }
    }

    lsum += __shfl_xor(lsum, 16);
    lsum += __shfl_xor(lsum, 32);
    float inv = 1.f / lsum;

    const int b = bh >> 3, nh = bh & 7;
    size_t obase = ((size_t)b*LQ + q0 + col)*CDIM + (size_t)nh*HD;
#pragma unroll
    for (int t = 0; t < 6; ++t) {
        bf16x4 qres = *(const bf16x4*)&Qp[(size_t)col*HD + t*16 + g*4];
        bf16x4 ov;
#pragma unroll
        for (int r = 0; r < 4; ++r)
            ov[r] = (bf16)(o[t][r]*inv + (float)qres[r]);
        *(bf16x4*)&out[obase + t*16 + g*4] = ov;
    }
}

extern "C" void kernel_launch(void* const* d_in, const int* in_sizes, int n_in,
                              void* d_out, int out_size, void* d_ws, size_t ws_size,
                              hipStream_t stream) {
    const float* x      = (const float*)d_in[0];
    const float* qkv_w  = (const float*)d_in[1];
    const float* qkv_b  = (const float*)d_in[2];
    const float* proj_w = (const float*)d_in[3];
    const float* proj_b = (const float*)d_in[4];
    const float* pq_w   = (const float*)d_in[5];
    const float* pk_w   = (const float*)d_in[6];
    const float* pv_w   = (const float*)d_in[7];

    uint8_t* ws = (uint8_t*)d_ws;
    bf16* x_bf     = (bf16*)(ws);                  // 77,070,336 B  [2][L0][768]
    bf16* qg_out   = (bf16*)(ws +  77070336);      // 77,070,336 B  [16][L0][96] (GELU'd Q)
    bf16* kv_c     = (bf16*)(ws + 154140672);      // 19,660,800 B  [2][16][3200][96]
    bf16* wqkv_bf  = (bf16*)(ws + 173801472);      // 3,538,944 B
    bf16* wproj_bf = (bf16*)(ws + 177340416);      // 1,179,648 B
    bf16* q_bf     = (bf16*)(ws + 178520064);      // 19,267,584 B  [16][6272][96]
    bf16* k_bf     = (bf16*)(ws + 197787648);      // 1,277,952 B   [16][416][96]
    bf16* vt_bf    = (bf16*)(ws + 199065600);      // 1,277,952 B   [16][96][416]
    bf16* attn_o   = (bf16*)(ws + 200343552);      // 19,267,584 B -> end 219,611,136

    cvt_all<<<2560, 256, 0, stream>>>((const f4*)x, (const f4*)qkv_w, (const f4*)proj_w,
                                      (bf16x4*)x_bf, (bf16x4*)wqkv_bf, (bf16x4*)wproj_bf);

    // merged Q + KV GEMM (2952 blocks, one dispatch, bf16 A via global_load_lds)
    gemm_qkv<<<NBQ + NBKV, 256, 0, stream>>>(x_bf, wqkv_bf, qkv_b, qg_out, kv_c);

    // merged convs (q + k + v + pad-zeroing, one dispatch)
    dwconv_all<<<668, 256, 0, stream>>>(qg_out, kv_c, pq_w, pk_w, pv_w,
                                        q_bf, k_bf, vt_bf);

    attn_mfma<<<16*(LQ/64), 256, 0, stream>>>(q_bf, k_bf, vt_bf, attn_o);

    gemm_proj<<<6*98, 256, 0, stream>>>(
        attn_o, wproj_bf, proj_b, (float*)d_out, 12544, 768, 768, 6);
}